// Round 15
// baseline (37.227 us; speedup 1.0000x reference)
//
#include <hip/hip_runtime.h>
#include <hip/hip_bf16.h>
#include <math.h>

// DDRFMixer: out[b,t,d] = sum_n softmax_n(x[b,t,:]·W[n,:]) * x[b,t-off_n,d]
// x: [B,T,D] fp32, W: [7,D] fp32, out: [B,T,D] fp32
// B=4, T=4096, D=1024, offsets = {1,2,4,8,16,32,64}
//
// R14 = R8 (best: 34.4 us) made PERSISTENT:
//  - Grid = 1024 blocks x 512 thr = exactly 4 blocks/CU = 32 waves/CU =
//    full residency in ONE dispatch round (R8's 2048 blocks = 16384 waves
//    needed two rounds: two occupancy ramps + 2048 block launch/retire +
//    per-block cold W-staging stalls).
//  - Each wave grid-strides to a second row (row + 8192): same per-row body,
//    W staged once per block for 16 rows instead of 8.
//  - Row->block mapping per round is identical to R8's (contiguous chunks
//    per XCD via the bijective swizzle), so L2 tap locality is unchanged.
// Kept verbatim from R8: W in LDS, DPP wave reduce, tap prefetch before the
// reduce (clamp+mask causality), no-max softmax, 1-ahead k-pipeline, plain
// float4 stores.

#define N_TAPS 7
#define DIM 1024
#define T_LEN 4096
#define BLOCK_THREADS 512
#define ROWS_PER_BLOCK 8     // one wave per row per round
#define N_BLOCKS 1024        // 4 blocks/CU on 256 CUs -> fully resident
#define ROUNDS 2             // 16384 rows / (1024 blocks * 8 rows)

// ---- DPP helpers: canonical GCN wave64 sum ----
template <int CTRL>
__device__ __forceinline__ float dpp_mov0(float v) {
    return __builtin_bit_cast(float,
        __builtin_amdgcn_update_dpp(0, __builtin_bit_cast(int, v),
                                    CTRL, 0xf, 0xf, true));
}
__device__ __forceinline__ float wave_sum_bcast(float v) {
    v += dpp_mov0<0x111>(v);   // row_shr:1
    v += dpp_mov0<0x112>(v);   // row_shr:2
    v += dpp_mov0<0x114>(v);   // row_shr:4
    v += dpp_mov0<0x118>(v);   // row_shr:8
    v += dpp_mov0<0x142>(v);   // row_bcast:15
    v += dpp_mov0<0x143>(v);   // row_bcast:31 -> lane63 = total
    return __builtin_bit_cast(float,
        __builtin_amdgcn_readlane(__builtin_bit_cast(int, v), 63));
}

__device__ __forceinline__ void process_row(
    const float* __restrict__ x,
    const float* __restrict__ wlds,
    float* __restrict__ out,
    int row, int lane)
{
    constexpr int offs[N_TAPS] = {1, 2, 4, 8, 16, 32, 64};

    const int t = row & (T_LEN - 1);
    const int dofs = lane * 4;
    const float* xrow = x + (size_t)row * DIM;

    // ---- this row's 16 elements (issue first; dots wait on these) ----
    float4 xv[4];
#pragma unroll
    for (int k = 0; k < 4; ++k)
        xv[k] = *reinterpret_cast<const float4*>(xrow + k * 256 + dofs);

    // ---- causal clamp + mask (branch-free => tap loads can issue now) ----
    const float* trow[N_TAPS];
    float tmask[N_TAPS];
#pragma unroll
    for (int n = 0; n < N_TAPS; ++n) {
        const bool ok = (t >= offs[n]);
        trow[n]  = xrow - (size_t)(ok ? offs[n] : 0) * DIM;
        tmask[n] = ok ? 1.0f : 0.0f;
    }

    // ---- prefetch k=0 taps: in flight across the reduce+softmax chain ----
    float4 tap[N_TAPS];
#pragma unroll
    for (int n = 0; n < N_TAPS; ++n)
        tap[n] = *reinterpret_cast<const float4*>(trow[n] + dofs);

    // ---- Phase 1: partial dots vs W (from LDS, parallel pipe) ----
    float p[N_TAPS];
#pragma unroll
    for (int n = 0; n < N_TAPS; ++n) {
        const float* wrow = &wlds[n * DIM];
        float4 w0 = *reinterpret_cast<const float4*>(wrow + 0 * 256 + dofs);
        float4 w1 = *reinterpret_cast<const float4*>(wrow + 1 * 256 + dofs);
        float4 w2 = *reinterpret_cast<const float4*>(wrow + 2 * 256 + dofs);
        float4 w3 = *reinterpret_cast<const float4*>(wrow + 3 * 256 + dofs);
        float s0 = fmaf(xv[0].x, w0.x, fmaf(xv[0].y, w0.y, fmaf(xv[0].z, w0.z, xv[0].w * w0.w)));
        float s1 = fmaf(xv[1].x, w1.x, fmaf(xv[1].y, w1.y, fmaf(xv[1].z, w1.z, xv[1].w * w1.w)));
        float s2 = fmaf(xv[2].x, w2.x, fmaf(xv[2].y, w2.y, fmaf(xv[2].z, w2.z, xv[2].w * w2.w)));
        float s3 = fmaf(xv[3].x, w3.x, fmaf(xv[3].y, w3.y, fmaf(xv[3].z, w3.z, xv[3].w * w3.w)));
        p[n] = (s0 + s1) + (s2 + s3);
    }

    // ---- DPP wave reduce (VALU pipe; 7 independent chains) ----
#pragma unroll
    for (int n = 0; n < N_TAPS; ++n)
        p[n] = wave_sum_bcast(p[n]);

    // ---- softmax over 7 taps (no max subtraction; logits small) + mask ----
    float wn[N_TAPS];
    float wsum = 0.f;
#pragma unroll
    for (int n = 0; n < N_TAPS; ++n) {
        wn[n] = __expf(p[n]);
        wsum += wn[n];
    }
    const float inv = 1.0f / wsum;
    float weff[N_TAPS];
#pragma unroll
    for (int n = 0; n < N_TAPS; ++n) weff[n] = wn[n] * inv * tmask[n];

    // ---- Phase 2: combine, 1-chunk-ahead pipeline over k ----
    float* orow = out + (size_t)row * DIM;
#pragma unroll
    for (int k = 0; k < 4; ++k) {
        float4 nxt[N_TAPS];
        if (k < 3) {
#pragma unroll
            for (int n = 0; n < N_TAPS; ++n)
                nxt[n] = *reinterpret_cast<const float4*>(
                    trow[n] + (k + 1) * 256 + dofs);
        }
        float4 a = make_float4(0.f, 0.f, 0.f, 0.f);
#pragma unroll
        for (int n = 0; n < N_TAPS; ++n) {
            a.x = fmaf(weff[n], tap[n].x, a.x);
            a.y = fmaf(weff[n], tap[n].y, a.y);
            a.z = fmaf(weff[n], tap[n].z, a.z);
            a.w = fmaf(weff[n], tap[n].w, a.w);
        }
        *reinterpret_cast<float4*>(orow + k * 256 + dofs) = a;
        if (k < 3) {
#pragma unroll
            for (int n = 0; n < N_TAPS; ++n) tap[n] = nxt[n];
        }
    }
}

__global__ __launch_bounds__(BLOCK_THREADS) void ddrf_mixer_kernel(
    const float* __restrict__ x,   // [B*T, D]
    const float* __restrict__ W,   // [N_TAPS, D]
    float* __restrict__ out,       // [B*T, D]
    int n_rows)
{
    __shared__ float wlds[N_TAPS * DIM];   // 28 KB

    // ---- stage W into LDS (ONCE per block, serves 16 rows) ----
    for (int i = threadIdx.x; i < N_TAPS * (DIM / 4); i += BLOCK_THREADS) {
        reinterpret_cast<float4*>(wlds)[i] =
            reinterpret_cast<const float4*>(W)[i];
    }
    __syncthreads();

    // ---- bijective XCD swizzle over the resident grid (1024 % 8 == 0) ----
    const int per = gridDim.x >> 3;
    const int wg  = (blockIdx.x & 7) * per + (blockIdx.x >> 3);

    const int wave = threadIdx.x >> 6;
    const int lane = threadIdx.x & 63;

    // ---- persistent grid-stride: round r covers rows [r*8192, (r+1)*8192) ----
    const int stride_rows = gridDim.x * ROWS_PER_BLOCK;   // 8192
#pragma unroll
    for (int r = 0; r < ROUNDS; ++r) {
        const int row = r * stride_rows + wg * ROWS_PER_BLOCK + wave;
        if (row < n_rows)
            process_row(x, wlds, out, row, lane);
    }
}

extern "C" void kernel_launch(void* const* d_in, const int* in_sizes, int n_in,
                              void* d_out, int out_size, void* d_ws, size_t ws_size,
                              hipStream_t stream) {
    const float* x = (const float*)d_in[0];   // [B,T,D] fp32
    const float* W = (const float*)d_in[1];   // [N_TAPS,D] fp32
    float* out = (float*)d_out;               // [B,T,D] fp32

    const int n_rows = in_sizes[0] / DIM;     // B*T = 16384

    ddrf_mixer_kernel<<<N_BLOCKS, BLOCK_THREADS, 0, stream>>>(x, W, out, n_rows);
}